// Round 1
// baseline (460.359 us; speedup 1.0000x reference)
//
#include <hip/hip_runtime.h>

#define DEV __device__ __forceinline__

typedef short bf16x8 __attribute__((ext_vector_type(8)));
typedef float f32x4  __attribute__((ext_vector_type(4)));

// Problem constants
// L=577, BT=128, D=768, B=16, T=8, H=W=24, CM=192, CR=48, K=3
// M = L*BT = 73856

DEV unsigned short f2bf(float f) {
  unsigned u = __float_as_uint(f);
  unsigned r = (u + 0x7fffu + ((u >> 16) & 1u)) >> 16;
  return (unsigned short)r;
}

DEV float silu_g(float v) {
  // v * sigmoid(1.702*v)
  return v / (1.f + __expf(-1.702f * v));
}

// ---------------------------------------------------------------------------
// Weight prep: transpose + cast to bf16, K-contiguous rows for MFMA B frags.
// w_preT[n*768 + k] = bf16(w_pre[k*192 + n])   (n<192, k<768)
// w_projT[n*192 + k] = bf16(w_proj[k*768 + n]) (n<768, k<192)
// ---------------------------------------------------------------------------
__global__ __launch_bounds__(256)
void prep_kernel(const float* __restrict__ w_pre, const float* __restrict__ w_proj,
                 short* __restrict__ w_preT, short* __restrict__ w_projT) {
  int i = blockIdx.x * 256 + threadIdx.x;
  if (i < 192 * 768) {
    int n = i / 768, k = i - n * 768;
    w_preT[i] = (short)f2bf(w_pre[k * 192 + n]);
    int n2 = i / 192, k2 = i - n2 * 192;
    w_projT[i] = (short)f2bf(w_proj[k2 * 768 + n2]);
  }
}

// ---------------------------------------------------------------------------
// MFMA GEMM: C[M x NTOT] = A[M x KTOT] * B[KTOT x NTOT] + bias
//   A: fp32 (cast to bf16 on stage) or bf16, row-major
//   Bt: bf16, transposed [NTOT][KTOT] (K-contiguous)
// Block: 256 thr = 4 waves (2x2), tile 128x64, BK=64.
// Wave tile 64x32 = 4x2 frags of 16x16, mfma_f32_16x16x32_bf16.
// ---------------------------------------------------------------------------
template<bool A_BF16, int KTOT, int NTOT>
__global__ __launch_bounds__(256)
void mfma_gemm(const void* __restrict__ A_, const short* __restrict__ Bt,
               const float* __restrict__ bias, float* __restrict__ C) {
  constexpr int BM = 128, BK = 64, LDT = BK + 8;
  __shared__ short As[BM][LDT];
  __shared__ short Bs[64][LDT];

  const int tid = threadIdx.x;
  const int m0 = blockIdx.x * BM;
  const int n0 = blockIdx.y * 64;
  const int wid = tid >> 6, lane = tid & 63;
  const int wm = wid >> 1, wn = wid & 1;
  const int lr = lane & 15, lk = (lane >> 4) * 8;

  f32x4 acc[4][2] = {};

  for (int kt = 0; kt < KTOT; kt += BK) {
    if constexpr (A_BF16) {
      const short* A = (const short*)A_;
      #pragma unroll
      for (int it = 0; it < 4; ++it) {
        int g = tid + it * 256;           // 1024 groups of 8 bf16
        int r = g >> 3, ko = (g & 7) * 8;
        *(uint4*)&As[r][ko] =
            *(const uint4*)(A + (size_t)(m0 + r) * KTOT + kt + ko);
      }
    } else {
      const float* A = (const float*)A_;
      #pragma unroll
      for (int it = 0; it < 8; ++it) {
        int g = tid + it * 256;           // 2048 groups of 4 fp32
        int r = g >> 4, ko = (g & 15) * 4;
        float4 v = *(const float4*)(A + (size_t)(m0 + r) * KTOT + kt + ko);
        short4 sv;
        sv.x = (short)f2bf(v.x); sv.y = (short)f2bf(v.y);
        sv.z = (short)f2bf(v.z); sv.w = (short)f2bf(v.w);
        *(short4*)&As[r][ko] = sv;
      }
    }
    #pragma unroll
    for (int it = 0; it < 2; ++it) {
      int g = tid + it * 256;             // 512 groups of 8 bf16
      int r = g >> 3, ko = (g & 7) * 8;
      *(uint4*)&Bs[r][ko] =
          *(const uint4*)(Bt + (size_t)(n0 + r) * KTOT + kt + ko);
    }
    __syncthreads();

    #pragma unroll
    for (int ks = 0; ks < BK; ks += 32) {
      bf16x8 af[4], bfr[2];
      #pragma unroll
      for (int fm = 0; fm < 4; ++fm)
        af[fm] = *(const bf16x8*)&As[wm * 64 + fm * 16 + lr][ks + lk];
      #pragma unroll
      for (int fn = 0; fn < 2; ++fn)
        bfr[fn] = *(const bf16x8*)&Bs[wn * 32 + fn * 16 + lr][ks + lk];
      #pragma unroll
      for (int fm = 0; fm < 4; ++fm)
        #pragma unroll
        for (int fn = 0; fn < 2; ++fn)
          acc[fm][fn] = __builtin_amdgcn_mfma_f32_16x16x32_bf16(
              af[fm], bfr[fn], acc[fm][fn], 0, 0, 0);
    }
    __syncthreads();
  }

  const int rb = (lane >> 4) * 4;
  #pragma unroll
  for (int fn = 0; fn < 2; ++fn) {
    int col = n0 + wn * 32 + fn * 16 + lr;
    float bv = bias[col];
    #pragma unroll
    for (int fm = 0; fm < 4; ++fm) {
      int row = m0 + wm * 64 + fm * 16 + rb;
      #pragma unroll
      for (int j = 0; j < 4; ++j)
        C[(size_t)(row + j) * NTOT + col] = acc[fm][fn][j] + bv;
    }
  }
}

// ---------------------------------------------------------------------------
// d[bt][c] = mean over l=1..576 of h[(l*128+bt)*192 + c]
// grid (128, 8), block 192; atomicAdd partials (d pre-zeroed).
// ---------------------------------------------------------------------------
__global__ __launch_bounds__(192)
void reduce_d_kernel(const float* __restrict__ h, float* __restrict__ d) {
  int bt = blockIdx.x, chunk = blockIdx.y, c = threadIdx.x;
  int l0 = 1 + chunk * 72;
  float sum = 0.f;
  #pragma unroll 8
  for (int i = 0; i < 72; ++i)
    sum += h[(size_t)((l0 + i) * 128 + bt) * 192 + c];
  atomicAdd(&d[bt * 192 + c], sum * (1.f / 576.f));
}

// ---------------------------------------------------------------------------
// Small path: g = mean_t(d) @ w_g + b_g; e = d + g;
// a = relu(conv1d(e, w_a) + b_a); alpha = conv1d(a, w_b) + 1
// grid (16) blocks (one per b), 192 threads.
// ---------------------------------------------------------------------------
__global__ __launch_bounds__(192)
void small_path_kernel(const float* __restrict__ d,
                       const float* __restrict__ w_g, const float* __restrict__ b_g,
                       const float* __restrict__ w_a, const float* __restrict__ b_a,
                       const float* __restrict__ w_b,
                       float* __restrict__ alpha) {
  int b = blockIdx.x, tid = threadIdx.x;
  __shared__ float e[8][192];
  __shared__ float md[192];
  __shared__ float g[192];
  __shared__ float a[8][48];

  #pragma unroll
  for (int t = 0; t < 8; ++t) e[t][tid] = d[(b * 8 + t) * 192 + tid];
  __syncthreads();
  float m = 0.f;
  #pragma unroll
  for (int t = 0; t < 8; ++t) m += e[t][tid];
  md[tid] = m * 0.125f;
  __syncthreads();

  float accg = b_g[tid];
  #pragma unroll 4
  for (int k = 0; k < 192; ++k) accg += md[k] * w_g[k * 192 + tid];
  g[tid] = accg;
  __syncthreads();
  #pragma unroll
  for (int t = 0; t < 8; ++t) e[t][tid] += g[tid];
  __syncthreads();

  for (int o = tid; o < 384; o += 192) {
    int t = o / 48, r = o - t * 48;
    float acc = b_a[r];
    #pragma unroll
    for (int dt = 0; dt < 3; ++dt) {
      int tt = t + dt - 1;
      if ((unsigned)tt < 8u) {
        #pragma unroll 4
        for (int k = 0; k < 192; ++k)
          acc += e[tt][k] * w_a[(dt * 192 + k) * 48 + r];
      }
    }
    a[t][r] = fmaxf(acc, 0.f);
  }
  __syncthreads();

  for (int t = 0; t < 8; ++t) {
    float acc = 1.0f;
    #pragma unroll
    for (int dt = 0; dt < 3; ++dt) {
      int tt = t + dt - 1;
      if ((unsigned)tt < 8u) {
        #pragma unroll 4
        for (int r = 0; r < 48; ++r)
          acc += a[tt][r] * w_b[(dt * 48 + r) * 192 + tid];
      }
    }
    alpha[(b * 8 + t) * 192 + tid] = acc;
  }
}

// ---------------------------------------------------------------------------
// Depthwise 3x3 conv + alpha scale + b_conv + cls passthrough + SiLU -> s(bf16)
// grid (128 bt, 6 c-chunks of 32), 256 threads.
// LDS: full 24x24 spatial plane for 32 channels (72 KB).
// ---------------------------------------------------------------------------
__global__ __launch_bounds__(256)
void dwconv_silu_kernel(const float* __restrict__ h, const float* __restrict__ alpha,
                        const float* __restrict__ w_base, const float* __restrict__ b_conv,
                        unsigned short* __restrict__ s) {
  const int bt = blockIdx.x, c0 = blockIdx.y * 32;
  const int tid = threadIdx.x;
  __shared__ float tile[576][32];

  // load spatial plane (float4 over 4 channels)
  #pragma unroll
  for (int it = 0; it < 18; ++it) {
    int gidx = tid + it * 256;            // 4608 groups of 4
    int p = gidx >> 3, cc = (gidx & 7) * 4;
    *(float4*)&tile[p][cc] =
        *(const float4*)(h + (size_t)((1 + p) * 128 + bt) * 192 + c0 + cc);
  }

  const int c = tid & 31;
  const int prow = tid >> 5;              // 0..7
  float wv[3][3];
  #pragma unroll
  for (int dh = 0; dh < 3; ++dh)
    #pragma unroll
    for (int dw = 0; dw < 3; ++dw)
      wv[dh][dw] = w_base[(dh * 3 + dw) * 192 + c0 + c];
  const float av = alpha[bt * 192 + c0 + c];
  const float bc = b_conv[c0 + c];

  // cls token row (l=0): pure SiLU passthrough
  if (tid < 32) {
    float v = h[(size_t)bt * 192 + c0 + tid];
    s[(size_t)bt * 192 + c0 + tid] = f2bf(silu_g(v));
  }
  __syncthreads();

  for (int i = 0; i < 72; ++i) {
    int p = prow + i * 8;                 // 0..575
    int hh = p / 24, ww = p - hh * 24;
    float acc = 0.f;
    #pragma unroll
    for (int dh = 0; dh < 3; ++dh) {
      int y = hh + dh - 1;
      if ((unsigned)y >= 24u) continue;
      #pragma unroll
      for (int dw = 0; dw < 3; ++dw) {
        int xx = ww + dw - 1;
        if ((unsigned)xx >= 24u) continue;
        acc += tile[y * 24 + xx][c] * wv[dh][dw];
      }
    }
    float pre = acc * av + bc;
    s[(size_t)((1 + p) * 128 + bt) * 192 + c0 + c] = f2bf(silu_g(pre));
  }
}

// ---------------------------------------------------------------------------
extern "C" void kernel_launch(void* const* d_in, const int* in_sizes, int n_in,
                              void* d_out, int out_size, void* d_ws, size_t ws_size,
                              hipStream_t stream) {
  (void)in_sizes; (void)n_in; (void)out_size; (void)ws_size;
  const float* x      = (const float*)d_in[0];
  const float* w_pre  = (const float*)d_in[1];
  const float* b_pre  = (const float*)d_in[2];
  const float* w_base = (const float*)d_in[3];
  const float* b_conv = (const float*)d_in[4];
  const float* w_g    = (const float*)d_in[5];
  const float* b_g    = (const float*)d_in[6];
  const float* w_a    = (const float*)d_in[7];
  const float* b_a    = (const float*)d_in[8];
  const float* w_b    = (const float*)d_in[9];
  const float* w_proj = (const float*)d_in[10];
  const float* b_proj = (const float*)d_in[11];

  float* out = (float*)d_out;
  float* h   = (float*)d_out;             // h (57 MB) lives in front of out;
                                          // only overwritten by final GEMM2.
  char* ws = (char*)d_ws;
  short* w_preT  = (short*)(ws);                  // 294912 B
  short* w_projT = (short*)(ws + 294912);         // 294912 B
  float* dbuf    = (float*)(ws + 589824);         //  98304 B
  float* alpha   = (float*)(ws + 688128);         //  98304 B
  short* s       = (short*)(ws + 786432);         // 28360704 B  (~29.1 MB total)

  prep_kernel<<<576, 256, 0, stream>>>(w_pre, w_proj, w_preT, w_projT);

  // GEMM1: h = x @ w_pre + b_pre   (M=73856, K=768, N=192)
  mfma_gemm<false, 768, 192><<<dim3(577, 3), 256, 0, stream>>>(x, w_preT, b_pre, h);

  hipMemsetAsync(dbuf, 0, 24576 * 4, stream);
  reduce_d_kernel<<<dim3(128, 8), 192, 0, stream>>>(h, dbuf);
  small_path_kernel<<<16, 192, 0, stream>>>(dbuf, w_g, b_g, w_a, b_a, w_b, alpha);
  dwconv_silu_kernel<<<dim3(128, 6), 256, 0, stream>>>(h, alpha, w_base, b_conv,
                                                       (unsigned short*)s);

  // GEMM2: out = s @ w_proj + b_proj   (M=73856, K=192, N=768)
  mfma_gemm<true, 192, 768><<<dim3(577, 12), 256, 0, stream>>>(s, w_projT, b_proj, out);
}

// Round 2
// 400.606 us; speedup vs baseline: 1.1492x; 1.1492x over previous
//
#include <hip/hip_runtime.h>

#define DEV __device__ __forceinline__

typedef short bf16x8 __attribute__((ext_vector_type(8)));
typedef float f32x4  __attribute__((ext_vector_type(4)));

// L=577, BT=128, D=768, B=16, T=8, H=W=24, CM=192, CR=48, K=3, M=L*BT=73856

DEV unsigned short f2bf(float f) {
  unsigned u = __float_as_uint(f);
  unsigned r = (u + 0x7fffu + ((u >> 16) & 1u)) >> 16;
  return (unsigned short)r;
}

DEV float silu_g(float v) { return v / (1.f + __expf(-1.702f * v)); }

DEV void gload_lds16(const void* g, void* l) {
  __builtin_amdgcn_global_load_lds(
      (const __attribute__((address_space(1))) unsigned int*)g,
      (__attribute__((address_space(3))) unsigned int*)l, 16, 0, 0);
}

// ---------------------------------------------------------------------------
// Weight prep: transpose + cast to bf16, K-contiguous rows for MFMA B frags.
// ---------------------------------------------------------------------------
__global__ __launch_bounds__(256)
void prep_kernel(const float* __restrict__ w_pre, const float* __restrict__ w_proj,
                 short* __restrict__ w_preT, short* __restrict__ w_projT) {
  int i = blockIdx.x * 256 + threadIdx.x;
  if (i < 192 * 768) {
    int n = i / 768, k = i - n * 768;
    w_preT[i] = (short)f2bf(w_pre[k * 192 + n]);
    int n2 = i / 192, k2 = i - n2 * 192;
    w_projT[i] = (short)f2bf(w_proj[k2 * 768 + n2]);
  }
}

// ---------------------------------------------------------------------------
// MFMA GEMM: C[M x NTOT] = A[M x KTOT] * B + bias, BM=128, BN=192 (full 192
// per block), BK=64. 512 thr = 8 waves (2M x 4N), wave tile 64x48 = 4x3 frags.
// LDS linear [row][64] bf16 with XOR chunk swizzle (chunk ^= row&7):
//   - bf16 operands staged via global_load_lds (pre-swizzled global source)
//   - fp32 A (GEMM1) reg-staged with cvt, next-tile loads issued under MFMA
// ---------------------------------------------------------------------------
template<bool A_BF16, int KTOT, int NTOT>
__global__ __launch_bounds__(512)
void gemm_kernel(const void* __restrict__ A_, const short* __restrict__ Bt,
                 const float* __restrict__ bias, float* __restrict__ C) {
  constexpr int BM = 128, BN = 192, BK = 64;
  __shared__ short As[BM * BK];   // 16 KB
  __shared__ short Bs[BN * BK];   // 24 KB

  const int tid  = threadIdx.x;
  const int wave = tid >> 6, lane = tid & 63;
  const int m0 = blockIdx.x * BM;
  const int n0 = blockIdx.y * BN;
  const int wm = wave >> 2, wn = wave & 3;
  const int lr  = lane & 15;
  const int lk8 = lane >> 4;          // 0..3 (k sub-chunk)
  const int srow = lane >> 3;         // 0..7  staging row-in-block
  const int schunk = lane & 7;        // 0..7  staging 16B slot

  const float* Af = (const float*)A_;
  const short* Ab = (const short*)A_;

  f32x4 acc[4][3] = {};
  float4 areg[2][2];

  auto loadA_f32 = [&](int kt) {
    #pragma unroll
    for (int s = 0; s < 2; ++s) {
      int id = tid + s * 512;
      int r = id >> 3, c = id & 7;
      int cg = c ^ (r & 7);
      const float* p = Af + (size_t)(m0 + r) * KTOT + kt + cg * 8;
      areg[s][0] = *(const float4*)p;
      areg[s][1] = *(const float4*)(p + 4);
    }
  };

  if constexpr (!A_BF16) loadA_f32(0);

  for (int kt = 0; kt < KTOT; kt += BK) {
    // ---- stage ----
    if constexpr (A_BF16) {
      #pragma unroll
      for (int j = 0; j < 2; ++j) {
        int rb8 = wave * 2 + j;               // 16 row-blocks of 8
        int r = rb8 * 8 + srow;
        int cg = schunk ^ (srow);             // r&7 == srow
        const short* src = Ab + (size_t)(m0 + r) * KTOT + kt + cg * 8;
        gload_lds16(src, (char*)As + rb8 * 1024);
      }
    } else {
      #pragma unroll
      for (int s = 0; s < 2; ++s) {
        int id = tid + s * 512;
        int r = id >> 3, c = id & 7;
        int4 w;
        w.x = f2bf(areg[s][0].x) | ((unsigned)f2bf(areg[s][0].y) << 16);
        w.y = f2bf(areg[s][0].z) | ((unsigned)f2bf(areg[s][0].w) << 16);
        w.z = f2bf(areg[s][1].x) | ((unsigned)f2bf(areg[s][1].y) << 16);
        w.w = f2bf(areg[s][1].z) | ((unsigned)f2bf(areg[s][1].w) << 16);
        *(int4*)&As[r * 64 + c * 8] = w;
      }
    }
    #pragma unroll
    for (int j = 0; j < 3; ++j) {
      int rb8 = wave * 3 + j;                 // 24 row-blocks of 8
      int r = rb8 * 8 + srow;
      int cg = schunk ^ (srow);
      const short* src = Bt + (size_t)(n0 + r) * KTOT + kt + cg * 8;
      gload_lds16(src, (char*)Bs + rb8 * 1024);
    }
    __syncthreads();   // drains vmcnt (global_load_lds) + lgkmcnt (ds_write)

    if constexpr (!A_BF16) {
      if (kt + BK < KTOT) loadA_f32(kt + BK);   // next tile, hides under MFMA
    }

    // ---- compute ----
    #pragma unroll
    for (int ks = 0; ks < 2; ++ks) {
      int kc = ks * 4 + lk8;                  // 16B chunk index 0..7
      bf16x8 af[4], bfv[3];
      #pragma unroll
      for (int fm = 0; fm < 4; ++fm) {
        int row = wm * 64 + fm * 16 + lr;
        af[fm] = *(const bf16x8*)&As[row * 64 + (kc ^ (row & 7)) * 8];
      }
      #pragma unroll
      for (int fn = 0; fn < 3; ++fn) {
        int row = wn * 48 + fn * 16 + lr;
        bfv[fn] = *(const bf16x8*)&Bs[row * 64 + (kc ^ (row & 7)) * 8];
      }
      #pragma unroll
      for (int fm = 0; fm < 4; ++fm)
        #pragma unroll
        for (int fn = 0; fn < 3; ++fn)
          acc[fm][fn] = __builtin_amdgcn_mfma_f32_16x16x32_bf16(
              af[fm], bfv[fn], acc[fm][fn], 0, 0, 0);
    }
    __syncthreads();
  }

  // ---- epilogue ----
  const int rb = (lane >> 4) * 4;
  #pragma unroll
  for (int fn = 0; fn < 3; ++fn) {
    int col = n0 + wn * 48 + fn * 16 + lr;
    float bv = bias[col];
    #pragma unroll
    for (int fm = 0; fm < 4; ++fm) {
      int row = m0 + wm * 64 + fm * 16 + rb;
      #pragma unroll
      for (int j = 0; j < 4; ++j)
        C[(size_t)(row + j) * NTOT + col] = acc[fm][fn][j] + bv;
    }
  }
}

// ---------------------------------------------------------------------------
// d[bt][c] = mean over l=1..576 of h[(l*128+bt)*192 + c]
// ---------------------------------------------------------------------------
__global__ __launch_bounds__(192)
void reduce_d_kernel(const float* __restrict__ h, float* __restrict__ d) {
  int bt = blockIdx.x, chunk = blockIdx.y, c = threadIdx.x;
  int l0 = 1 + chunk * 72;
  float sum = 0.f;
  #pragma unroll 8
  for (int i = 0; i < 72; ++i)
    sum += h[(size_t)((l0 + i) * 128 + bt) * 192 + c];
  atomicAdd(&d[bt * 192 + c], sum * (1.f / 576.f));
}

// ---------------------------------------------------------------------------
// Small path: g = mean_t(d) @ w_g + b_g; e = d + g;
// a = relu(conv1d(e, w_a) + b_a); alpha = conv1d(a, w_b) + 1
// ---------------------------------------------------------------------------
__global__ __launch_bounds__(192)
void small_path_kernel(const float* __restrict__ d,
                       const float* __restrict__ w_g, const float* __restrict__ b_g,
                       const float* __restrict__ w_a, const float* __restrict__ b_a,
                       const float* __restrict__ w_b,
                       float* __restrict__ alpha) {
  int b = blockIdx.x, tid = threadIdx.x;
  __shared__ float e[8][192];
  __shared__ float md[192];
  __shared__ float g[192];
  __shared__ float a[8][48];

  #pragma unroll
  for (int t = 0; t < 8; ++t) e[t][tid] = d[(b * 8 + t) * 192 + tid];
  __syncthreads();
  float m = 0.f;
  #pragma unroll
  for (int t = 0; t < 8; ++t) m += e[t][tid];
  md[tid] = m * 0.125f;
  __syncthreads();

  float accg = b_g[tid];
  #pragma unroll 4
  for (int k = 0; k < 192; ++k) accg += md[k] * w_g[k * 192 + tid];
  g[tid] = accg;
  __syncthreads();
  #pragma unroll
  for (int t = 0; t < 8; ++t) e[t][tid] += g[tid];
  __syncthreads();

  for (int o = tid; o < 384; o += 192) {
    int t = o / 48, r = o - t * 48;
    float acc = b_a[r];
    #pragma unroll
    for (int dt = 0; dt < 3; ++dt) {
      int tt = t + dt - 1;
      if ((unsigned)tt < 8u) {
        #pragma unroll 4
        for (int k = 0; k < 192; ++k)
          acc += e[tt][k] * w_a[(dt * 192 + k) * 48 + r];
      }
    }
    a[t][r] = fmaxf(acc, 0.f);
  }
  __syncthreads();

  for (int t = 0; t < 8; ++t) {
    float acc = 1.0f;
    #pragma unroll
    for (int dt = 0; dt < 3; ++dt) {
      int tt = t + dt - 1;
      if ((unsigned)tt < 8u) {
        #pragma unroll 4
        for (int r = 0; r < 48; ++r)
          acc += a[tt][r] * w_b[(dt * 48 + r) * 192 + tid];
      }
    }
    alpha[(b * 8 + t) * 192 + tid] = acc;
  }
}

// ---------------------------------------------------------------------------
// Depthwise 3x3 conv + alpha scale + b_conv + cls passthrough + SiLU -> s(bf16)
// ---------------------------------------------------------------------------
__global__ __launch_bounds__(256)
void dwconv_silu_kernel(const float* __restrict__ h, const float* __restrict__ alpha,
                        const float* __restrict__ w_base, const float* __restrict__ b_conv,
                        unsigned short* __restrict__ s) {
  const int bt = blockIdx.x, c0 = blockIdx.y * 32;
  const int tid = threadIdx.x;
  __shared__ float tile[576][32];

  #pragma unroll
  for (int it = 0; it < 18; ++it) {
    int gidx = tid + it * 256;
    int p = gidx >> 3, cc = (gidx & 7) * 4;
    *(float4*)&tile[p][cc] =
        *(const float4*)(h + (size_t)((1 + p) * 128 + bt) * 192 + c0 + cc);
  }

  const int c = tid & 31;
  const int prow = tid >> 5;
  float wv[3][3];
  #pragma unroll
  for (int dh = 0; dh < 3; ++dh)
    #pragma unroll
    for (int dw = 0; dw < 3; ++dw)
      wv[dh][dw] = w_base[(dh * 3 + dw) * 192 + c0 + c];
  const float av = alpha[bt * 192 + c0 + c];
  const float bc = b_conv[c0 + c];

  if (tid < 32) {
    float v = h[(size_t)bt * 192 + c0 + tid];
    s[(size_t)bt * 192 + c0 + tid] = f2bf(silu_g(v));
  }
  __syncthreads();

  for (int i = 0; i < 72; ++i) {
    int p = prow + i * 8;
    int hh = p / 24, ww = p - hh * 24;
    float acc = 0.f;
    #pragma unroll
    for (int dh = 0; dh < 3; ++dh) {
      int y = hh + dh - 1;
      if ((unsigned)y >= 24u) continue;
      #pragma unroll
      for (int dw = 0; dw < 3; ++dw) {
        int xx = ww + dw - 1;
        if ((unsigned)xx >= 24u) continue;
        acc += tile[y * 24 + xx][c] * wv[dh][dw];
      }
    }
    float pre = acc * av + bc;
    s[(size_t)((1 + p) * 128 + bt) * 192 + c0 + c] = f2bf(silu_g(pre));
  }
}

// ---------------------------------------------------------------------------
extern "C" void kernel_launch(void* const* d_in, const int* in_sizes, int n_in,
                              void* d_out, int out_size, void* d_ws, size_t ws_size,
                              hipStream_t stream) {
  (void)in_sizes; (void)n_in; (void)out_size; (void)ws_size;
  const float* x      = (const float*)d_in[0];
  const float* w_pre  = (const float*)d_in[1];
  const float* b_pre  = (const float*)d_in[2];
  const float* w_base = (const float*)d_in[3];
  const float* b_conv = (const float*)d_in[4];
  const float* w_g    = (const float*)d_in[5];
  const float* b_g    = (const float*)d_in[6];
  const float* w_a    = (const float*)d_in[7];
  const float* b_a    = (const float*)d_in[8];
  const float* w_b    = (const float*)d_in[9];
  const float* w_proj = (const float*)d_in[10];
  const float* b_proj = (const float*)d_in[11];

  float* out = (float*)d_out;
  float* h   = (float*)d_out;             // h (57 MB) in front of out
  char* ws = (char*)d_ws;
  short* w_preT  = (short*)(ws);                  // 294912 B
  short* w_projT = (short*)(ws + 294912);         // 294912 B
  float* dbuf    = (float*)(ws + 589824);         //  98304 B
  float* alpha   = (float*)(ws + 688128);         //  98304 B
  short* s       = (short*)(ws + 786432);         // 28360704 B

  prep_kernel<<<576, 256, 0, stream>>>(w_pre, w_proj, w_preT, w_projT);

  // GEMM1: h = x @ w_pre + b_pre   (M=73856, K=768, N=192)
  gemm_kernel<false, 768, 192><<<dim3(577, 1), 512, 0, stream>>>(x, w_preT, b_pre, h);

  hipMemsetAsync(dbuf, 0, 24576 * 4, stream);
  reduce_d_kernel<<<dim3(128, 8), 192, 0, stream>>>(h, dbuf);
  small_path_kernel<<<16, 192, 0, stream>>>(dbuf, w_g, b_g, w_a, b_a, w_b, alpha);
  dwconv_silu_kernel<<<dim3(128, 6), 256, 0, stream>>>(h, alpha, w_base, b_conv,
                                                       (unsigned short*)s);

  // GEMM2: out = s @ w_proj + b_proj   (M=73856, K=192, N=768)
  gemm_kernel<true, 192, 768><<<dim3(577, 4), 512, 0, stream>>>(s, w_projT, b_proj, out);
}

// Round 3
// 300.835 us; speedup vs baseline: 1.5303x; 1.3316x over previous
//
#include <hip/hip_runtime.h>

#define DEV __device__ __forceinline__

typedef short bf16x8 __attribute__((ext_vector_type(8)));
typedef float f32x4  __attribute__((ext_vector_type(4)));

// L=577, BT=128, D=768, B=16, T=8, H=W=24, CM=192, CR=48, K=3, M=L*BT=73856

DEV unsigned short f2bf(float f) {
  unsigned u = __float_as_uint(f);
  unsigned r = (u + 0x7fffu + ((u >> 16) & 1u)) >> 16;
  return (unsigned short)r;
}

DEV float bf2f(unsigned short b) { return __uint_as_float((unsigned)b << 16); }

DEV float silu_g(float v) { return v / (1.f + __expf(-1.702f * v)); }

DEV void gload_lds16(const void* g, void* l) {
  __builtin_amdgcn_global_load_lds(
      (const __attribute__((address_space(1))) unsigned int*)g,
      (__attribute__((address_space(3))) unsigned int*)l, 16, 0, 0);
}

// ---------------------------------------------------------------------------
// Weight prep: transpose + cast to bf16, K-contiguous rows for MFMA B frags.
// ---------------------------------------------------------------------------
__global__ __launch_bounds__(256)
void prep_kernel(const float* __restrict__ w_pre, const float* __restrict__ w_proj,
                 short* __restrict__ w_preT, short* __restrict__ w_projT) {
  int i = blockIdx.x * 256 + threadIdx.x;
  if (i < 192 * 768) {
    int n = i / 768, k = i - n * 768;
    w_preT[i] = (short)f2bf(w_pre[k * 192 + n]);
    int n2 = i / 192, k2 = i - n2 * 192;
    w_projT[i] = (short)f2bf(w_proj[k2 * 768 + n2]);
  }
}

// ---------------------------------------------------------------------------
// MFMA GEMM: C[M x NTOT] = A[M x KTOT] * B + bias, BM=128, BN=192, BK=64.
// 512 thr = 8 waves (2M x 4N), wave tile 64x48 = 4x3 frags of 16x16x32.
// LDS linear [row][64] bf16 with XOR chunk swizzle (chunk ^= row&7).
// ---------------------------------------------------------------------------
template<bool A_BF16, int KTOT, int NTOT>
__global__ __launch_bounds__(512)
void gemm_kernel(const void* __restrict__ A_, const short* __restrict__ Bt,
                 const float* __restrict__ bias, float* __restrict__ C) {
  constexpr int BM = 128, BN = 192, BK = 64;
  __shared__ short As[BM * BK];   // 16 KB
  __shared__ short Bs[BN * BK];   // 24 KB

  const int tid  = threadIdx.x;
  const int wave = tid >> 6, lane = tid & 63;
  const int m0 = blockIdx.x * BM;
  const int n0 = blockIdx.y * BN;
  const int wm = wave >> 2, wn = wave & 3;
  const int lr  = lane & 15;
  const int lk8 = lane >> 4;
  const int srow = lane >> 3;
  const int schunk = lane & 7;

  const float* Af = (const float*)A_;
  const short* Ab = (const short*)A_;

  f32x4 acc[4][3] = {};
  float4 areg[2][2];

  auto loadA_f32 = [&](int kt) {
    #pragma unroll
    for (int s = 0; s < 2; ++s) {
      int id = tid + s * 512;
      int r = id >> 3, c = id & 7;
      int cg = c ^ (r & 7);
      const float* p = Af + (size_t)(m0 + r) * KTOT + kt + cg * 8;
      areg[s][0] = *(const float4*)p;
      areg[s][1] = *(const float4*)(p + 4);
    }
  };

  if constexpr (!A_BF16) loadA_f32(0);

  for (int kt = 0; kt < KTOT; kt += BK) {
    if constexpr (A_BF16) {
      #pragma unroll
      for (int j = 0; j < 2; ++j) {
        int rb8 = wave * 2 + j;
        int r = rb8 * 8 + srow;
        int cg = schunk ^ (srow);
        const short* src = Ab + (size_t)(m0 + r) * KTOT + kt + cg * 8;
        gload_lds16(src, (char*)As + rb8 * 1024);
      }
    } else {
      #pragma unroll
      for (int s = 0; s < 2; ++s) {
        int id = tid + s * 512;
        int r = id >> 3, c = id & 7;
        int4 w;
        w.x = f2bf(areg[s][0].x) | ((unsigned)f2bf(areg[s][0].y) << 16);
        w.y = f2bf(areg[s][0].z) | ((unsigned)f2bf(areg[s][0].w) << 16);
        w.z = f2bf(areg[s][1].x) | ((unsigned)f2bf(areg[s][1].y) << 16);
        w.w = f2bf(areg[s][1].z) | ((unsigned)f2bf(areg[s][1].w) << 16);
        *(int4*)&As[r * 64 + c * 8] = w;
      }
    }
    #pragma unroll
    for (int j = 0; j < 3; ++j) {
      int rb8 = wave * 3 + j;
      int r = rb8 * 8 + srow;
      int cg = schunk ^ (srow);
      const short* src = Bt + (size_t)(n0 + r) * KTOT + kt + cg * 8;
      gload_lds16(src, (char*)Bs + rb8 * 1024);
    }
    __syncthreads();

    if constexpr (!A_BF16) {
      if (kt + BK < KTOT) loadA_f32(kt + BK);
    }

    #pragma unroll
    for (int ks = 0; ks < 2; ++ks) {
      int kc = ks * 4 + lk8;
      bf16x8 af[4], bfv[3];
      #pragma unroll
      for (int fm = 0; fm < 4; ++fm) {
        int row = wm * 64 + fm * 16 + lr;
        af[fm] = *(const bf16x8*)&As[row * 64 + (kc ^ (row & 7)) * 8];
      }
      #pragma unroll
      for (int fn = 0; fn < 3; ++fn) {
        int row = wn * 48 + fn * 16 + lr;
        bfv[fn] = *(const bf16x8*)&Bs[row * 64 + (kc ^ (row & 7)) * 8];
      }
      #pragma unroll
      for (int fm = 0; fm < 4; ++fm)
        #pragma unroll
        for (int fn = 0; fn < 3; ++fn)
          acc[fm][fn] = __builtin_amdgcn_mfma_f32_16x16x32_bf16(
              af[fm], bfv[fn], acc[fm][fn], 0, 0, 0);
    }
    __syncthreads();
  }

  const int rb = (lane >> 4) * 4;
  #pragma unroll
  for (int fn = 0; fn < 3; ++fn) {
    int col = n0 + wn * 48 + fn * 16 + lr;
    float bv = bias[col];
    #pragma unroll
    for (int fm = 0; fm < 4; ++fm) {
      int row = m0 + wm * 64 + fm * 16 + rb;
      #pragma unroll
      for (int j = 0; j < 4; ++j)
        C[(size_t)(row + j) * NTOT + col] = acc[fm][fn][j] + bv;
    }
  }
}

// ---------------------------------------------------------------------------
// d[bt][c] = mean over l=1..576 of h[(l*128+bt)*192 + c]
// ---------------------------------------------------------------------------
__global__ __launch_bounds__(192)
void reduce_d_kernel(const float* __restrict__ h, float* __restrict__ d) {
  int bt = blockIdx.x, chunk = blockIdx.y, c = threadIdx.x;
  int l0 = 1 + chunk * 72;
  float sum = 0.f;
  #pragma unroll 8
  for (int i = 0; i < 72; ++i)
    sum += h[(size_t)((l0 + i) * 128 + bt) * 192 + c];
  atomicAdd(&d[bt * 192 + c], sum * (1.f / 576.f));
}

// ---------------------------------------------------------------------------
// Small path, LDS-staged weights (bf16). One block per b, 256 threads.
// Phases: [stage w_g | load d] -> md -> g -> e | [stage w_a] -> a |
//         [stage w_b] -> alpha.
// All dot-product loops read LDS (broadcast / 2-way aliasing = free), so the
// per-thread serial global-load latency chain of the old version is gone.
// ---------------------------------------------------------------------------
__global__ __launch_bounds__(256)
void small_path_kernel(const float* __restrict__ d,
                       const float* __restrict__ w_g, const float* __restrict__ b_g,
                       const float* __restrict__ w_a, const float* __restrict__ b_a,
                       const float* __restrict__ w_b,
                       float* __restrict__ alpha) {
  const int b = blockIdx.x, tid = threadIdx.x;
  __shared__ unsigned short wbuf[36864];   // 72 KB, reused per phase
  __shared__ float e[8][192];
  __shared__ float md[192];
  __shared__ float a[8][48];

  // ---- stage w_g (bf16) + load d into e ----
  #pragma unroll
  for (int it = 0; it < 36; ++it) {        // 36864/4 = 9216 float4 groups
    int i = tid + it * 256;
    float4 v = *(const float4*)(w_g + i * 4);
    short4 sv;
    sv.x = (short)f2bf(v.x); sv.y = (short)f2bf(v.y);
    sv.z = (short)f2bf(v.z); sv.w = (short)f2bf(v.w);
    *(short4*)&wbuf[i * 4] = sv;
  }
  #pragma unroll
  for (int i = tid; i < 384; i += 256)     // 1536 floats
    *(float4*)((float*)e + i * 4) = *(const float4*)(d + (size_t)b * 1536 + i * 4);
  __syncthreads();

  // ---- md = mean over t ----
  if (tid < 192) {
    float m = 0.f;
    #pragma unroll
    for (int t = 0; t < 8; ++t) m += e[t][tid];
    md[tid] = m * 0.125f;
  }
  __syncthreads();

  // ---- g = md @ w_g + b_g; e += g ----
  if (tid < 192) {
    float accg = b_g[tid];
    #pragma unroll 8
    for (int k = 0; k < 192; ++k)
      accg += md[k] * bf2f(wbuf[k * 192 + tid]);
    #pragma unroll
    for (int t = 0; t < 8; ++t) e[t][tid] += accg;
  }
  __syncthreads();

  // ---- stage w_a (bf16) ----
  #pragma unroll
  for (int it = 0; it < 27; ++it) {        // 27648/4 = 6912 float4 groups
    int i = tid + it * 256;
    float4 v = *(const float4*)(w_a + i * 4);
    short4 sv;
    sv.x = (short)f2bf(v.x); sv.y = (short)f2bf(v.y);
    sv.z = (short)f2bf(v.z); sv.w = (short)f2bf(v.w);
    *(short4*)&wbuf[i * 4] = sv;
  }
  __syncthreads();

  // ---- a = relu(conv1d(e, w_a) + b_a) ----
  for (int o = tid; o < 384; o += 256) {
    int t = o / 48, r = o - t * 48;
    float acc = b_a[r];
    #pragma unroll
    for (int dt = 0; dt < 3; ++dt) {
      int tt = t + dt - 1;
      if ((unsigned)tt < 8u) {
        #pragma unroll 8
        for (int k = 0; k < 192; ++k)
          acc += e[tt][k] * bf2f(wbuf[(dt * 192 + k) * 48 + r]);
      }
    }
    a[t][r] = fmaxf(acc, 0.f);
  }
  __syncthreads();

  // ---- stage w_b (bf16) ----
  #pragma unroll
  for (int it = 0; it < 27; ++it) {
    int i = tid + it * 256;
    float4 v = *(const float4*)(w_b + i * 4);
    short4 sv;
    sv.x = (short)f2bf(v.x); sv.y = (short)f2bf(v.y);
    sv.z = (short)f2bf(v.z); sv.w = (short)f2bf(v.w);
    *(short4*)&wbuf[i * 4] = sv;
  }
  __syncthreads();

  // ---- alpha = conv1d(a, w_b) + 1 ----
  if (tid < 192) {
    #pragma unroll
    for (int t = 0; t < 8; ++t) {
      float acc = 1.0f;
      #pragma unroll
      for (int dt = 0; dt < 3; ++dt) {
        int tt = t + dt - 1;
        if ((unsigned)tt < 8u) {
          #pragma unroll 8
          for (int r = 0; r < 48; ++r)
            acc += a[tt][r] * bf2f(wbuf[(dt * 48 + r) * 192 + tid]);
        }
      }
      alpha[(size_t)(b * 8 + t) * 192 + tid] = acc;
    }
  }
}

// ---------------------------------------------------------------------------
// Depthwise 3x3 conv + alpha scale + b_conv + cls passthrough + SiLU -> s(bf16)
// ---------------------------------------------------------------------------
__global__ __launch_bounds__(256)
void dwconv_silu_kernel(const float* __restrict__ h, const float* __restrict__ alpha,
                        const float* __restrict__ w_base, const float* __restrict__ b_conv,
                        unsigned short* __restrict__ s) {
  const int bt = blockIdx.x, c0 = blockIdx.y * 32;
  const int tid = threadIdx.x;
  __shared__ float tile[576][32];

  #pragma unroll
  for (int it = 0; it < 18; ++it) {
    int gidx = tid + it * 256;
    int p = gidx >> 3, cc = (gidx & 7) * 4;
    *(float4*)&tile[p][cc] =
        *(const float4*)(h + (size_t)((1 + p) * 128 + bt) * 192 + c0 + cc);
  }

  const int c = tid & 31;
  const int prow = tid >> 5;
  float wv[3][3];
  #pragma unroll
  for (int dh = 0; dh < 3; ++dh)
    #pragma unroll
    for (int dw = 0; dw < 3; ++dw)
      wv[dh][dw] = w_base[(dh * 3 + dw) * 192 + c0 + c];
  const float av = alpha[bt * 192 + c0 + c];
  const float bc = b_conv[c0 + c];

  if (tid < 32) {
    float v = h[(size_t)bt * 192 + c0 + tid];
    s[(size_t)bt * 192 + c0 + tid] = f2bf(silu_g(v));
  }
  __syncthreads();

  for (int i = 0; i < 72; ++i) {
    int p = prow + i * 8;
    int hh = p / 24, ww = p - hh * 24;
    float acc = 0.f;
    #pragma unroll
    for (int dh = 0; dh < 3; ++dh) {
      int y = hh + dh - 1;
      if ((unsigned)y >= 24u) continue;
      #pragma unroll
      for (int dw = 0; dw < 3; ++dw) {
        int xx = ww + dw - 1;
        if ((unsigned)xx >= 24u) continue;
        acc += tile[y * 24 + xx][c] * wv[dh][dw];
      }
    }
    float pre = acc * av + bc;
    s[(size_t)((1 + p) * 128 + bt) * 192 + c0 + c] = f2bf(silu_g(pre));
  }
}

// ---------------------------------------------------------------------------
extern "C" void kernel_launch(void* const* d_in, const int* in_sizes, int n_in,
                              void* d_out, int out_size, void* d_ws, size_t ws_size,
                              hipStream_t stream) {
  (void)in_sizes; (void)n_in; (void)out_size; (void)ws_size;
  const float* x      = (const float*)d_in[0];
  const float* w_pre  = (const float*)d_in[1];
  const float* b_pre  = (const float*)d_in[2];
  const float* w_base = (const float*)d_in[3];
  const float* b_conv = (const float*)d_in[4];
  const float* w_g    = (const float*)d_in[5];
  const float* b_g    = (const float*)d_in[6];
  const float* w_a    = (const float*)d_in[7];
  const float* b_a    = (const float*)d_in[8];
  const float* w_b    = (const float*)d_in[9];
  const float* w_proj = (const float*)d_in[10];
  const float* b_proj = (const float*)d_in[11];

  float* out = (float*)d_out;
  float* h   = (float*)d_out;             // h (57 MB) in front of out
  char* ws = (char*)d_ws;
  short* w_preT  = (short*)(ws);                  // 294912 B
  short* w_projT = (short*)(ws + 294912);         // 294912 B
  float* dbuf    = (float*)(ws + 589824);         //  98304 B
  float* alpha   = (float*)(ws + 688128);         //  98304 B
  short* s       = (short*)(ws + 786432);         // 28360704 B

  prep_kernel<<<576, 256, 0, stream>>>(w_pre, w_proj, w_preT, w_projT);

  // GEMM1: h = x @ w_pre + b_pre   (M=73856, K=768, N=192)
  gemm_kernel<false, 768, 192><<<dim3(577, 1), 512, 0, stream>>>(x, w_preT, b_pre, h);

  hipMemsetAsync(dbuf, 0, 24576 * 4, stream);
  reduce_d_kernel<<<dim3(128, 8), 192, 0, stream>>>(h, dbuf);
  small_path_kernel<<<16, 256, 0, stream>>>(dbuf, w_g, b_g, w_a, b_a, w_b, alpha);
  dwconv_silu_kernel<<<dim3(128, 6), 256, 0, stream>>>(h, alpha, w_base, b_conv,
                                                       (unsigned short*)s);

  // GEMM2: out = s @ w_proj + b_proj   (M=73856, K=192, N=768)
  gemm_kernel<true, 192, 768><<<dim3(577, 4), 512, 0, stream>>>(s, w_projT, b_proj, out);
}

// Round 5
// 292.637 us; speedup vs baseline: 1.5731x; 1.0280x over previous
//
#include <hip/hip_runtime.h>

#define DEV __device__ __forceinline__

typedef short bf16x8 __attribute__((ext_vector_type(8)));
typedef float f32x4  __attribute__((ext_vector_type(4)));

// L=577, BT=128, D=768, B=16, T=8, H=W=24, CM=192, CR=48, K=3, M=L*BT=73856

DEV unsigned short f2bf(float f) {
  unsigned u = __float_as_uint(f);
  unsigned r = (u + 0x7fffu + ((u >> 16) & 1u)) >> 16;
  return (unsigned short)r;
}

DEV unsigned cvt_pk_bf16(float a, float b) {   // {lo:bf16(a), hi:bf16(b)} RNE
  unsigned r;
  asm("v_cvt_pk_bf16_f32 %0, %1, %2" : "=v"(r) : "v"(a), "v"(b));
  return r;
}

DEV float bf2f(unsigned short b) { return __uint_as_float((unsigned)b << 16); }

DEV float silu_g(float v) { return v / (1.f + __expf(-1.702f * v)); }

DEV void gload_lds16(const void* g, void* l) {
  __builtin_amdgcn_global_load_lds(
      (const __attribute__((address_space(1))) unsigned int*)g,
      (__attribute__((address_space(3))) unsigned int*)l, 16, 0, 0);
}

// ---------------------------------------------------------------------------
// Weight prep: transpose + cast to bf16, K-contiguous rows for MFMA B frags.
// ---------------------------------------------------------------------------
__global__ __launch_bounds__(256)
void prep_kernel(const float* __restrict__ w_pre, const float* __restrict__ w_proj,
                 short* __restrict__ w_preT, short* __restrict__ w_projT) {
  int i = blockIdx.x * 256 + threadIdx.x;
  if (i < 192 * 768) {
    int n = i / 768, k = i - n * 768;
    w_preT[i] = (short)f2bf(w_pre[k * 192 + n]);
    int n2 = i / 192, k2 = i - n2 * 192;
    w_projT[i] = (short)f2bf(w_proj[k2 * 768 + n2]);
  }
}

// ---------------------------------------------------------------------------
// MFMA GEMM: C[M x NTOT] = A[M x KTOT] * B + bias, BM=128, BN=192, BK=64.
// 512 thr = 8 waves (2M x 4N), wave tile 64x48 = 4x3 frags of 16x16x32.
// LDS linear [row][64] bf16 with XOR chunk swizzle (chunk ^= row&7).
// MFMA called as mfma(B_frag, A_frag): reg-axis = N cols, lane&15 = M row
// -> each lane holds 4 consecutive N cols => float4 C stores.
// ---------------------------------------------------------------------------
template<bool A_BF16, int KTOT, int NTOT, bool NT_STORE>
__global__ __launch_bounds__(512)
void gemm_kernel(const void* __restrict__ A_, const short* __restrict__ Bt,
                 const float* __restrict__ bias, float* __restrict__ C) {
  constexpr int BM = 128, BN = 192, BK = 64;
  __shared__ short As[BM * BK];   // 16 KB
  __shared__ short Bs[BN * BK];   // 24 KB

  const int tid  = threadIdx.x;
  const int wave = tid >> 6, lane = tid & 63;
  const int m0 = blockIdx.x * BM;
  const int n0 = blockIdx.y * BN;
  const int wm = wave >> 2, wn = wave & 3;
  const int lr  = lane & 15;
  const int lk8 = lane >> 4;
  const int srow = lane >> 3;
  const int schunk = lane & 7;

  const float* Af = (const float*)A_;
  const short* Ab = (const short*)A_;

  f32x4 acc[4][3] = {};
  float4 areg[2][2];

  auto loadA_f32 = [&](int kt) {
    #pragma unroll
    for (int s = 0; s < 2; ++s) {
      int id = tid + s * 512;
      int r = id >> 3, c = id & 7;
      int cg = c ^ (r & 7);
      const float* p = Af + (size_t)(m0 + r) * KTOT + kt + cg * 8;
      areg[s][0] = *(const float4*)p;
      areg[s][1] = *(const float4*)(p + 4);
    }
  };

  if constexpr (!A_BF16) loadA_f32(0);

  for (int kt = 0; kt < KTOT; kt += BK) {
    // ---- stage ----
    if constexpr (A_BF16) {
      #pragma unroll
      for (int j = 0; j < 2; ++j) {
        int rb8 = wave * 2 + j;
        int r = rb8 * 8 + srow;
        int cg = schunk ^ (srow);
        const short* src = Ab + (size_t)(m0 + r) * KTOT + kt + cg * 8;
        gload_lds16(src, (char*)As + rb8 * 1024);
      }
    } else {
      #pragma unroll
      for (int s = 0; s < 2; ++s) {
        int id = tid + s * 512;
        int r = id >> 3, c = id & 7;
        int4 w;
        w.x = (int)cvt_pk_bf16(areg[s][0].x, areg[s][0].y);
        w.y = (int)cvt_pk_bf16(areg[s][0].z, areg[s][0].w);
        w.z = (int)cvt_pk_bf16(areg[s][1].x, areg[s][1].y);
        w.w = (int)cvt_pk_bf16(areg[s][1].z, areg[s][1].w);
        *(int4*)&As[r * 64 + c * 8] = w;
      }
    }
    #pragma unroll
    for (int j = 0; j < 3; ++j) {
      int rb8 = wave * 3 + j;
      int r = rb8 * 8 + srow;
      int cg = schunk ^ (srow);
      const short* src = Bt + (size_t)(n0 + r) * KTOT + kt + cg * 8;
      gload_lds16(src, (char*)Bs + rb8 * 1024);
    }
    __syncthreads();

    if constexpr (!A_BF16) {
      if (kt + BK < KTOT) loadA_f32(kt + BK);   // next tile under MFMA
    }

    // ---- compute ----
    #pragma unroll
    for (int ks = 0; ks < 2; ++ks) {
      int kc = ks * 4 + lk8;
      bf16x8 af[4], bfv[3];
      #pragma unroll
      for (int fm = 0; fm < 4; ++fm) {
        int row = wm * 64 + fm * 16 + lr;
        af[fm] = *(const bf16x8*)&As[row * 64 + (kc ^ (row & 7)) * 8];
      }
      #pragma unroll
      for (int fn = 0; fn < 3; ++fn) {
        int row = wn * 48 + fn * 16 + lr;
        bfv[fn] = *(const bf16x8*)&Bs[row * 64 + (kc ^ (row & 7)) * 8];
      }
      #pragma unroll
      for (int fm = 0; fm < 4; ++fm)
        #pragma unroll
        for (int fn = 0; fn < 3; ++fn)
          acc[fm][fn] = __builtin_amdgcn_mfma_f32_16x16x32_bf16(
              bfv[fn], af[fm], acc[fm][fn], 0, 0, 0);
    }
    __syncthreads();
  }

  // ---- epilogue: float4 stores (reg-axis = N cols) ----
  const int cb = (lane >> 4) * 4;
  #pragma unroll
  for (int fm = 0; fm < 4; ++fm) {
    int row = m0 + wm * 64 + fm * 16 + lr;
    #pragma unroll
    for (int fn = 0; fn < 3; ++fn) {
      int col = n0 + wn * 48 + fn * 16 + cb;
      float4 bv = *(const float4*)(bias + col);
      f32x4 o;
      o[0] = acc[fm][fn][0] + bv.x;
      o[1] = acc[fm][fn][1] + bv.y;
      o[2] = acc[fm][fn][2] + bv.z;
      o[3] = acc[fm][fn][3] + bv.w;
      f32x4* dst = (f32x4*)&C[(size_t)row * NTOT + col];
      if constexpr (NT_STORE) __builtin_nontemporal_store(o, dst);
      else                    *dst = o;
    }
  }
}

// ---------------------------------------------------------------------------
// dpart[chunk][bt][c] = (1/576) * sum over 144 l's of h[(l*128+bt)*192 + c]
// grid (128, 4), block 192. No atomics, no zero-init needed.
// ---------------------------------------------------------------------------
__global__ __launch_bounds__(192)
void reduce_d_kernel(const float* __restrict__ h, float* __restrict__ dpart) {
  int bt = blockIdx.x, chunk = blockIdx.y, c = threadIdx.x;
  int l0 = 1 + chunk * 144;
  float sum = 0.f;
  #pragma unroll 8
  for (int i = 0; i < 144; ++i)
    sum += h[(size_t)((l0 + i) * 128 + bt) * 192 + c];
  dpart[(size_t)(chunk * 128 + bt) * 192 + c] = sum * (1.f / 576.f);
}

// ---------------------------------------------------------------------------
// Small path, LDS-staged weights (bf16). One block per b, 256 threads.
// d = sum of 4 partials (done during staging).
// ---------------------------------------------------------------------------
__global__ __launch_bounds__(256)
void small_path_kernel(const float* __restrict__ dpart,
                       const float* __restrict__ w_g, const float* __restrict__ b_g,
                       const float* __restrict__ w_a, const float* __restrict__ b_a,
                       const float* __restrict__ w_b,
                       float* __restrict__ alpha) {
  const int b = blockIdx.x, tid = threadIdx.x;
  __shared__ unsigned short wbuf[36864];   // 72 KB, reused per phase
  __shared__ float e[8][192];
  __shared__ float md[192];
  __shared__ float a[8][48];

  // ---- stage w_g (bf16) + load/sum d partials into e ----
  #pragma unroll
  for (int it = 0; it < 36; ++it) {
    int i = tid + it * 256;
    float4 v = *(const float4*)(w_g + i * 4);
    int2 w;
    w.x = (int)cvt_pk_bf16(v.x, v.y);
    w.y = (int)cvt_pk_bf16(v.z, v.w);
    *(int2*)&wbuf[i * 4] = w;
  }
  {
    const float4* dp4 = (const float4*)dpart;
    for (int i = tid; i < 384; i += 256) {
      float4 v0 = dp4[b * 384 + i];
      float4 v1 = dp4[6144 + b * 384 + i];
      float4 v2 = dp4[12288 + b * 384 + i];
      float4 v3 = dp4[18432 + b * 384 + i];
      float4 v;
      v.x = (v0.x + v1.x) + (v2.x + v3.x);
      v.y = (v0.y + v1.y) + (v2.y + v3.y);
      v.z = (v0.z + v1.z) + (v2.z + v3.z);
      v.w = (v0.w + v1.w) + (v2.w + v3.w);
      *(float4*)((float*)e + i * 4) = v;
    }
  }
  __syncthreads();

  // ---- md = mean over t ----
  if (tid < 192) {
    float m = 0.f;
    #pragma unroll
    for (int t = 0; t < 8; ++t) m += e[t][tid];
    md[tid] = m * 0.125f;
  }
  __syncthreads();

  // ---- g = md @ w_g + b_g; e += g ----
  if (tid < 192) {
    float accg = b_g[tid];
    #pragma unroll 8
    for (int k = 0; k < 192; ++k)
      accg += md[k] * bf2f(wbuf[k * 192 + tid]);
    #pragma unroll
    for (int t = 0; t < 8; ++t) e[t][tid] += accg;
  }
  __syncthreads();

  // ---- stage w_a (bf16) ----
  #pragma unroll
  for (int it = 0; it < 27; ++it) {
    int i = tid + it * 256;
    float4 v = *(const float4*)(w_a + i * 4);
    int2 w;
    w.x = (int)cvt_pk_bf16(v.x, v.y);
    w.y = (int)cvt_pk_bf16(v.z, v.w);
    *(int2*)&wbuf[i * 4] = w;
  }
  __syncthreads();

  // ---- a = relu(conv1d(e, w_a) + b_a) ----
  for (int o = tid; o < 384; o += 256) {
    int t = o / 48, r = o - t * 48;
    float acc = b_a[r];
    #pragma unroll
    for (int dt = 0; dt < 3; ++dt) {
      int tt = t + dt - 1;
      if ((unsigned)tt < 8u) {
        #pragma unroll 8
        for (int k = 0; k < 192; ++k)
          acc += e[tt][k] * bf2f(wbuf[(dt * 192 + k) * 48 + r]);
      }
    }
    a[t][r] = fmaxf(acc, 0.f);
  }
  __syncthreads();

  // ---- stage w_b (bf16) ----
  #pragma unroll
  for (int it = 0; it < 27; ++it) {
    int i = tid + it * 256;
    float4 v = *(const float4*)(w_b + i * 4);
    int2 w;
    w.x = (int)cvt_pk_bf16(v.x, v.y);
    w.y = (int)cvt_pk_bf16(v.z, v.w);
    *(int2*)&wbuf[i * 4] = w;
  }
  __syncthreads();

  // ---- alpha = conv1d(a, w_b) + 1 ----
  if (tid < 192) {
    #pragma unroll
    for (int t = 0; t < 8; ++t) {
      float acc = 1.0f;
      #pragma unroll
      for (int dt = 0; dt < 3; ++dt) {
        int tt = t + dt - 1;
        if ((unsigned)tt < 8u) {
          #pragma unroll 8
          for (int r = 0; r < 48; ++r)
            acc += a[tt][r] * bf2f(wbuf[(dt * 48 + r) * 192 + tid]);
        }
      }
      alpha[(size_t)(b * 8 + t) * 192 + tid] = acc;
    }
  }
}

// ---------------------------------------------------------------------------
// Depthwise 3x3 conv + alpha scale + b_conv + cls passthrough + SiLU -> s(bf16)
// ---------------------------------------------------------------------------
__global__ __launch_bounds__(256)
void dwconv_silu_kernel(const float* __restrict__ h, const float* __restrict__ alpha,
                        const float* __restrict__ w_base, const float* __restrict__ b_conv,
                        unsigned short* __restrict__ s) {
  const int bt = blockIdx.x, c0 = blockIdx.y * 32;
  const int tid = threadIdx.x;
  __shared__ float tile[576][32];

  #pragma unroll
  for (int it = 0; it < 18; ++it) {
    int gidx = tid + it * 256;
    int p = gidx >> 3, cc = (gidx & 7) * 4;
    *(float4*)&tile[p][cc] =
        *(const float4*)(h + (size_t)((1 + p) * 128 + bt) * 192 + c0 + cc);
  }

  const int c = tid & 31;
  const int prow = tid >> 5;
  float wv[3][3];
  #pragma unroll
  for (int dh = 0; dh < 3; ++dh)
    #pragma unroll
    for (int dw = 0; dw < 3; ++dw)
      wv[dh][dw] = w_base[(dh * 3 + dw) * 192 + c0 + c];
  const float av = alpha[bt * 192 + c0 + c];
  const float bc = b_conv[c0 + c];

  if (tid < 32) {
    float v = h[(size_t)bt * 192 + c0 + tid];
    s[(size_t)bt * 192 + c0 + tid] = f2bf(silu_g(v));
  }
  __syncthreads();

  for (int i = 0; i < 72; ++i) {
    int p = prow + i * 8;
    int hh = p / 24, ww = p - hh * 24;
    float acc = 0.f;
    #pragma unroll
    for (int dh = 0; dh < 3; ++dh) {
      int y = hh + dh - 1;
      if ((unsigned)y >= 24u) continue;
      #pragma unroll
      for (int dw = 0; dw < 3; ++dw) {
        int xx = ww + dw - 1;
        if ((unsigned)xx >= 24u) continue;
        acc += tile[y * 24 + xx][c] * wv[dh][dw];
      }
    }
    float pre = acc * av + bc;
    s[(size_t)((1 + p) * 128 + bt) * 192 + c0 + c] = f2bf(silu_g(pre));
  }
}

// ---------------------------------------------------------------------------
extern "C" void kernel_launch(void* const* d_in, const int* in_sizes, int n_in,
                              void* d_out, int out_size, void* d_ws, size_t ws_size,
                              hipStream_t stream) {
  (void)in_sizes; (void)n_in; (void)out_size; (void)ws_size;
  const float* x      = (const float*)d_in[0];
  const float* w_pre  = (const float*)d_in[1];
  const float* b_pre  = (const float*)d_in[2];
  const float* w_base = (const float*)d_in[3];
  const float* b_conv = (const float*)d_in[4];
  const float* w_g    = (const float*)d_in[5];
  const float* b_g    = (const float*)d_in[6];
  const float* w_a    = (const float*)d_in[7];
  const float* b_a    = (const float*)d_in[8];
  const float* w_b    = (const float*)d_in[9];
  const float* w_proj = (const float*)d_in[10];
  const float* b_proj = (const float*)d_in[11];

  float* out = (float*)d_out;
  float* h   = (float*)d_out;             // h (57 MB) in front of out
  char* ws = (char*)d_ws;
  short* w_preT  = (short*)(ws);                  //      0: 294912 B
  short* w_projT = (short*)(ws + 294912);         // 294912: 294912 B
  float* dbuf    = (float*)(ws + 589824);         // 589824: 393216 B (4 partials)
  float* alpha   = (float*)(ws + 983040);         // 983040:  98304 B
  short* s       = (short*)(ws + 1081344);        // 28360704 B

  prep_kernel<<<576, 256, 0, stream>>>(w_pre, w_proj, w_preT, w_projT);

  // GEMM1: h = x @ w_pre + b_pre   (M=73856, K=768, N=192)
  gemm_kernel<false, 768, 192, false><<<dim3(577, 1), 512, 0, stream>>>(
      x, w_preT, b_pre, h);

  reduce_d_kernel<<<dim3(128, 4), 192, 0, stream>>>(h, dbuf);
  small_path_kernel<<<16, 256, 0, stream>>>(dbuf, w_g, b_g, w_a, b_a, w_b, alpha);
  dwconv_silu_kernel<<<dim3(128, 6), 256, 0, stream>>>(h, alpha, w_base, b_conv,
                                                       (unsigned short*)s);

  // GEMM2: out = s @ w_proj + b_proj   (M=73856, K=192, N=768)
  gemm_kernel<true, 192, 768, true><<<dim3(577, 4), 512, 0, stream>>>(
      s, w_projT, b_proj, out);
}

// Round 6
// 247.143 us; speedup vs baseline: 1.8627x; 1.1841x over previous
//
#include <hip/hip_runtime.h>

#define DEV __device__ __forceinline__

typedef short bf16x8 __attribute__((ext_vector_type(8)));
typedef float f32x4  __attribute__((ext_vector_type(4)));
typedef unsigned short ushort_t;

// L=577, BT=128, D=768, B=16, T=8, H=W=24, CM=192, CR=48, K=3, M=L*BT=73856

DEV unsigned short f2bf(float f) {
  unsigned u = __float_as_uint(f);
  unsigned r = (u + 0x7fffu + ((u >> 16) & 1u)) >> 16;
  return (unsigned short)r;
}

DEV unsigned cvt_pk_bf16(float a, float b) {   // {lo:bf16(a), hi:bf16(b)} RNE
  unsigned r;
  asm("v_cvt_pk_bf16_f32 %0, %1, %2" : "=v"(r) : "v"(a), "v"(b));
  return r;
}

DEV float bf2f(unsigned short b) { return __uint_as_float((unsigned)b << 16); }

DEV float silu_g(float v) { return v / (1.f + __expf(-1.702f * v)); }

DEV void gload_lds16(const void* g, void* l) {
  __builtin_amdgcn_global_load_lds(
      (const __attribute__((address_space(1))) unsigned int*)g,
      (__attribute__((address_space(3))) unsigned int*)l, 16, 0, 0);
}

// ---------------------------------------------------------------------------
// Weight prep: transpose + cast to bf16, K-contiguous rows for MFMA B frags.
// ---------------------------------------------------------------------------
__global__ __launch_bounds__(256)
void prep_kernel(const float* __restrict__ w_pre, const float* __restrict__ w_proj,
                 short* __restrict__ w_preT, short* __restrict__ w_projT) {
  int i = blockIdx.x * 256 + threadIdx.x;
  if (i < 192 * 768) {
    int n = i / 768, k = i - n * 768;
    w_preT[i] = (short)f2bf(w_pre[k * 192 + n]);
    int n2 = i / 192, k2 = i - n2 * 192;
    w_projT[i] = (short)f2bf(w_proj[k2 * 768 + n2]);
  }
}

// ---------------------------------------------------------------------------
// MFMA GEMM, double-buffered (T3-minimal 2-phase): per iter
//   STAGE(next tile) -> compute(cur) -> one __syncthreads (drains vm+lgkm).
// BM=128, BN=192, BK=64, 512 thr = 8 waves (2M x 4N), wave tile 64x48.
// LDS [2] buffers, linear [row][64] bf16, XOR chunk swizzle (chunk ^= row&7).
// mfma(B_frag, A_frag): reg-axis = N cols -> vectorized C stores.
// OUT_BF16: pack 4 cols to 2x u32 (h output). Else fp32 float4 (+NT).
// ---------------------------------------------------------------------------
template<bool A_BF16, int KTOT, int NTOT, bool OUT_BF16, bool NT_STORE>
__global__ __launch_bounds__(512, 4)
void gemm_kernel(const void* __restrict__ A_, const short* __restrict__ Bt,
                 const float* __restrict__ bias, void* __restrict__ C_) {
  constexpr int BM = 128, BN = 192, BK = 64;
  constexpr int NT = KTOT / BK;
  __shared__ short As[2][BM * BK];   // 2x16 KB
  __shared__ short Bs[2][BN * BK];   // 2x24 KB

  const int tid  = threadIdx.x;
  const int wave = tid >> 6, lane = tid & 63;
  const int m0 = blockIdx.x * BM;
  const int n0 = blockIdx.y * BN;
  const int wm = wave >> 2, wn = wave & 3;
  const int lr  = lane & 15;
  const int lk8 = lane >> 4;
  const int srow = lane >> 3;
  const int schunk = lane & 7;

  const float* Af = (const float*)A_;
  const short* Ab = (const short*)A_;

  f32x4 acc[4][3] = {};
  float4 areg[2][2];   // fp32-A prefetch (consume at iter top, refill after)

  auto loadA_f32 = [&](int kt) {
    #pragma unroll
    for (int s = 0; s < 2; ++s) {
      int id = tid + s * 512;
      int r = id >> 3, c = id & 7;
      int cg = c ^ (r & 7);
      const float* p = Af + (size_t)(m0 + r) * KTOT + kt + cg * 8;
      areg[s][0] = *(const float4*)p;
      areg[s][1] = *(const float4*)(p + 4);
    }
  };
  auto cvtStoreA = [&](int buf) {
    #pragma unroll
    for (int s = 0; s < 2; ++s) {
      int id = tid + s * 512;
      int r = id >> 3, c = id & 7;
      int4 w;
      w.x = (int)cvt_pk_bf16(areg[s][0].x, areg[s][0].y);
      w.y = (int)cvt_pk_bf16(areg[s][0].z, areg[s][0].w);
      w.z = (int)cvt_pk_bf16(areg[s][1].x, areg[s][1].y);
      w.w = (int)cvt_pk_bf16(areg[s][1].z, areg[s][1].w);
      *(int4*)&As[buf][r * 64 + c * 8] = w;
    }
  };
  auto stageA16 = [&](int kt, int buf) {
    #pragma unroll
    for (int j = 0; j < 2; ++j) {
      int rb8 = wave * 2 + j;
      int r = rb8 * 8 + srow;
      const short* src = Ab + (size_t)(m0 + r) * KTOT + kt + (schunk ^ srow) * 8;
      gload_lds16(src, (char*)As[buf] + rb8 * 1024);
    }
  };
  auto stageB = [&](int kt, int buf) {
    #pragma unroll
    for (int j = 0; j < 3; ++j) {
      int rb8 = wave * 3 + j;
      int r = rb8 * 8 + srow;
      const short* src = Bt + (size_t)(n0 + r) * KTOT + kt + (schunk ^ srow) * 8;
      gload_lds16(src, (char*)Bs[buf] + rb8 * 1024);
    }
  };
  auto compute = [&](int buf) {
    #pragma unroll
    for (int ks = 0; ks < 2; ++ks) {
      int kc = ks * 4 + lk8;
      bf16x8 af[4], bfv[3];
      #pragma unroll
      for (int fm = 0; fm < 4; ++fm) {
        int row = wm * 64 + fm * 16 + lr;
        af[fm] = *(const bf16x8*)&As[buf][row * 64 + (kc ^ (row & 7)) * 8];
      }
      #pragma unroll
      for (int fn = 0; fn < 3; ++fn) {
        int row = wn * 48 + fn * 16 + lr;
        bfv[fn] = *(const bf16x8*)&Bs[buf][row * 64 + (kc ^ (row & 7)) * 8];
      }
      #pragma unroll
      for (int fm = 0; fm < 4; ++fm)
        #pragma unroll
        for (int fn = 0; fn < 3; ++fn)
          acc[fm][fn] = __builtin_amdgcn_mfma_f32_16x16x32_bf16(
              bfv[fn], af[fm], acc[fm][fn], 0, 0, 0);
    }
  };

  // ---- prologue: tile 0 into buf 0; prefetch A-regs for tile 1 ----
  if constexpr (!A_BF16) { loadA_f32(0); cvtStoreA(0); }
  else                   stageA16(0, 0);
  stageB(0, 0);
  if constexpr (!A_BF16) { if (NT > 1) loadA_f32(BK); }
  __syncthreads();

  // ---- main loop: stage(next) -> compute(cur) -> one barrier ----
  #pragma unroll
  for (int t = 0; t < NT; ++t) {
    const int cur = t & 1, nxt = cur ^ 1;
    if (t + 1 < NT) {
      if constexpr (!A_BF16) {
        cvtStoreA(nxt);                              // consume areg (tile t+1)
        if (t + 2 < NT) loadA_f32((t + 2) * BK);     // refill, flies under MFMA
      } else {
        stageA16((t + 1) * BK, nxt);
      }
      stageB((t + 1) * BK, nxt);
    }
    compute(cur);
    if (t + 1 < NT) __syncthreads();
  }

  // ---- epilogue (reg-axis = 4 consecutive N cols) ----
  const int cb = (lane >> 4) * 4;
  #pragma unroll
  for (int fm = 0; fm < 4; ++fm) {
    int row = m0 + wm * 64 + fm * 16 + lr;
    #pragma unroll
    for (int fn = 0; fn < 3; ++fn) {
      int col = n0 + wn * 48 + fn * 16 + cb;
      float4 bv = *(const float4*)(bias + col);
      float o0 = acc[fm][fn][0] + bv.x;
      float o1 = acc[fm][fn][1] + bv.y;
      float o2 = acc[fm][fn][2] + bv.z;
      float o3 = acc[fm][fn][3] + bv.w;
      if constexpr (OUT_BF16) {
        ushort_t* Cb = (ushort_t*)C_;
        int2 w;
        w.x = (int)cvt_pk_bf16(o0, o1);
        w.y = (int)cvt_pk_bf16(o2, o3);
        *(int2*)&Cb[(size_t)row * NTOT + col] = w;
      } else {
        float* Cf = (float*)C_;
        f32x4 o; o[0] = o0; o[1] = o1; o[2] = o2; o[3] = o3;
        f32x4* dst = (f32x4*)&Cf[(size_t)row * NTOT + col];
        if constexpr (NT_STORE) __builtin_nontemporal_store(o, dst);
        else                    *dst = o;
      }
    }
  }
}

// ---------------------------------------------------------------------------
// d[bt][c] = mean over l=1..576 of h_bf16[(l*128+bt)*192 + c]
// grid 128 (one per bt), 192 thr: slice=tid/24 covers 72 l's, c8=tid%24 covers
// 8 channels via bf16x8 loads; LDS slice-reduce. No atomics, no partial buf.
// ---------------------------------------------------------------------------
__global__ __launch_bounds__(192)
void reduce_d_kernel(const ushort_t* __restrict__ h, float* __restrict__ d) {
  const int bt = blockIdx.x, tid = threadIdx.x;
  const int slice = tid / 24, c8 = tid % 24;
  __shared__ float part[8][192];
  float sum[8] = {};
  #pragma unroll 4
  for (int i = 0; i < 72; ++i) {
    int l = 1 + slice * 72 + i;
    bf16x8 v = *(const bf16x8*)&h[((size_t)l * 128 + bt) * 192 + c8 * 8];
    #pragma unroll
    for (int j = 0; j < 8; ++j) sum[j] += bf2f((unsigned short)v[j]);
  }
  #pragma unroll
  for (int j = 0; j < 8; ++j) part[slice][c8 * 8 + j] = sum[j];
  __syncthreads();
  float s = 0.f;
  #pragma unroll
  for (int sl = 0; sl < 8; ++sl) s += part[sl][tid];
  d[bt * 192 + tid] = s * (1.f / 576.f);
}

// ---------------------------------------------------------------------------
// Small path, LDS-staged weights (bf16). One block per b, 256 threads.
// ---------------------------------------------------------------------------
__global__ __launch_bounds__(256)
void small_path_kernel(const float* __restrict__ d,
                       const float* __restrict__ w_g, const float* __restrict__ b_g,
                       const float* __restrict__ w_a, const float* __restrict__ b_a,
                       const float* __restrict__ w_b,
                       float* __restrict__ alpha) {
  const int b = blockIdx.x, tid = threadIdx.x;
  __shared__ unsigned short wbuf[36864];   // 72 KB, reused per phase
  __shared__ float e[8][192];
  __shared__ float md[192];
  __shared__ float a[8][48];

  // ---- stage w_g (bf16) + load d into e ----
  #pragma unroll
  for (int it = 0; it < 36; ++it) {
    int i = tid + it * 256;
    float4 v = *(const float4*)(w_g + i * 4);
    int2 w;
    w.x = (int)cvt_pk_bf16(v.x, v.y);
    w.y = (int)cvt_pk_bf16(v.z, v.w);
    *(int2*)&wbuf[i * 4] = w;
  }
  for (int i = tid; i < 384; i += 256)
    *(float4*)((float*)e + i * 4) = *(const float4*)(d + (size_t)b * 1536 + i * 4);
  __syncthreads();

  // ---- md = mean over t ----
  if (tid < 192) {
    float m = 0.f;
    #pragma unroll
    for (int t = 0; t < 8; ++t) m += e[t][tid];
    md[tid] = m * 0.125f;
  }
  __syncthreads();

  // ---- g = md @ w_g + b_g; e += g ----
  if (tid < 192) {
    float accg = b_g[tid];
    #pragma unroll 8
    for (int k = 0; k < 192; ++k)
      accg += md[k] * bf2f(wbuf[k * 192 + tid]);
    #pragma unroll
    for (int t = 0; t < 8; ++t) e[t][tid] += accg;
  }
  __syncthreads();

  // ---- stage w_a (bf16) ----
  #pragma unroll
  for (int it = 0; it < 27; ++it) {
    int i = tid + it * 256;
    float4 v = *(const float4*)(w_a + i * 4);
    int2 w;
    w.x = (int)cvt_pk_bf16(v.x, v.y);
    w.y = (int)cvt_pk_bf16(v.z, v.w);
    *(int2*)&wbuf[i * 4] = w;
  }
  __syncthreads();

  // ---- a = relu(conv1d(e, w_a) + b_a) ----
  for (int o = tid; o < 384; o += 256) {
    int t = o / 48, r = o - t * 48;
    float acc = b_a[r];
    #pragma unroll
    for (int dt = 0; dt < 3; ++dt) {
      int tt = t + dt - 1;
      if ((unsigned)tt < 8u) {
        #pragma unroll 8
        for (int k = 0; k < 192; ++k)
          acc += e[tt][k] * bf2f(wbuf[(dt * 192 + k) * 48 + r]);
      }
    }
    a[t][r] = fmaxf(acc, 0.f);
  }
  __syncthreads();

  // ---- stage w_b (bf16) ----
  #pragma unroll
  for (int it = 0; it < 27; ++it) {
    int i = tid + it * 256;
    float4 v = *(const float4*)(w_b + i * 4);
    int2 w;
    w.x = (int)cvt_pk_bf16(v.x, v.y);
    w.y = (int)cvt_pk_bf16(v.z, v.w);
    *(int2*)&wbuf[i * 4] = w;
  }
  __syncthreads();

  // ---- alpha = conv1d(a, w_b) + 1 ----
  if (tid < 192) {
    #pragma unroll
    for (int t = 0; t < 8; ++t) {
      float acc = 1.0f;
      #pragma unroll
      for (int dt = 0; dt < 3; ++dt) {
        int tt = t + dt - 1;
        if ((unsigned)tt < 8u) {
          #pragma unroll 8
          for (int r = 0; r < 48; ++r)
            acc += a[tt][r] * bf2f(wbuf[(dt * 48 + r) * 192 + tid]);
        }
      }
      alpha[(size_t)(b * 8 + t) * 192 + tid] = acc;
    }
  }
}

// ---------------------------------------------------------------------------
// Depthwise 3x3 conv + alpha scale + b_conv + cls passthrough + SiLU -> s(bf16)
// h is bf16 now: tile 36 KB -> 4 blocks/CU.
// ---------------------------------------------------------------------------
__global__ __launch_bounds__(256)
void dwconv_silu_kernel(const ushort_t* __restrict__ h, const float* __restrict__ alpha,
                        const float* __restrict__ w_base, const float* __restrict__ b_conv,
                        ushort_t* __restrict__ s) {
  const int bt = blockIdx.x, c0 = blockIdx.y * 32;
  const int tid = threadIdx.x;
  __shared__ ushort_t tile[576][32];   // 36 KB

  #pragma unroll
  for (int it = 0; it < 9; ++it) {
    int gidx = tid + it * 256;          // 2304 groups of 8 bf16 (16 B)
    int p = gidx >> 2, cc = (gidx & 3) * 8;
    *(bf16x8*)&tile[p][cc] =
        *(const bf16x8*)&h[((size_t)(1 + p) * 128 + bt) * 192 + c0 + cc];
  }

  const int c = tid & 31;
  const int prow = tid >> 5;
  float wv[3][3];
  #pragma unroll
  for (int dh = 0; dh < 3; ++dh)
    #pragma unroll
    for (int dw = 0; dw < 3; ++dw)
      wv[dh][dw] = w_base[(dh * 3 + dw) * 192 + c0 + c];
  const float av = alpha[bt * 192 + c0 + c];
  const float bc = b_conv[c0 + c];

  if (tid < 32) {
    float v = bf2f(h[(size_t)bt * 192 + c0 + tid]);
    s[(size_t)bt * 192 + c0 + tid] = f2bf(silu_g(v));
  }
  __syncthreads();

  for (int i = 0; i < 72; ++i) {
    int p = prow + i * 8;
    int hh = p / 24, ww = p - hh * 24;
    float acc = 0.f;
    #pragma unroll
    for (int dh = 0; dh < 3; ++dh) {
      int y = hh + dh - 1;
      if ((unsigned)y >= 24u) continue;
      #pragma unroll
      for (int dw = 0; dw < 3; ++dw) {
        int xx = ww + dw - 1;
        if ((unsigned)xx >= 24u) continue;
        acc += bf2f(tile[y * 24 + xx][c]) * wv[dh][dw];
      }
    }
    float pre = acc * av + bc;
    s[(size_t)((1 + p) * 128 + bt) * 192 + c0 + c] = f2bf(silu_g(pre));
  }
}

// ---------------------------------------------------------------------------
extern "C" void kernel_launch(void* const* d_in, const int* in_sizes, int n_in,
                              void* d_out, int out_size, void* d_ws, size_t ws_size,
                              hipStream_t stream) {
  (void)in_sizes; (void)n_in; (void)out_size; (void)ws_size;
  const float* x      = (const float*)d_in[0];
  const float* w_pre  = (const float*)d_in[1];
  const float* b_pre  = (const float*)d_in[2];
  const float* w_base = (const float*)d_in[3];
  const float* b_conv = (const float*)d_in[4];
  const float* w_g    = (const float*)d_in[5];
  const float* b_g    = (const float*)d_in[6];
  const float* w_a    = (const float*)d_in[7];
  const float* b_a    = (const float*)d_in[8];
  const float* w_b    = (const float*)d_in[9];
  const float* w_proj = (const float*)d_in[10];
  const float* b_proj = (const float*)d_in[11];

  float* out = (float*)d_out;
  ushort_t* h = (ushort_t*)d_out;         // h bf16 (28 MB) in front of out;
                                          // consumed before GEMM2 overwrites.
  char* ws = (char*)d_ws;
  short* w_preT  = (short*)(ws);                  //      0: 294912 B
  short* w_projT = (short*)(ws + 294912);         // 294912: 294912 B
  float* dbuf    = (float*)(ws + 589824);         // 589824:  98304 B
  float* alpha   = (float*)(ws + 688128);         // 688128:  98304 B
  short* s       = (short*)(ws + 786432);         // 28360704 B

  prep_kernel<<<576, 256, 0, stream>>>(w_pre, w_proj, w_preT, w_projT);

  // GEMM1: h(bf16) = x @ w_pre + b_pre   (M=73856, K=768, N=192)
  gemm_kernel<false, 768, 192, true, false><<<dim3(577, 1), 512, 0, stream>>>(
      x, w_preT, b_pre, h);

  reduce_d_kernel<<<128, 192, 0, stream>>>(h, dbuf);
  small_path_kernel<<<16, 256, 0, stream>>>(dbuf, w_g, b_g, w_a, b_a, w_b, alpha);
  dwconv_silu_kernel<<<dim3(128, 6), 256, 0, stream>>>(h, alpha, w_base, b_conv,
                                                       (ushort_t*)s);

  // GEMM2: out = s @ w_proj + b_proj   (M=73856, K=192, N=768)
  gemm_kernel<true, 192, 768, false, true><<<dim3(577, 4), 512, 0, stream>>>(
      s, w_projT, b_proj, out);
}